// Round 3
// baseline (148.422 us; speedup 1.0000x reference)
//
#include <hip/hip_runtime.h>
#include <math.h>

// ---------------------------------------------------------------------------
// Strict2_5DLoss — 3-level triangle detection loss, forward only.
//
// R2 -> R3:
//  * Block-type interleave (bid&3 -> {lvl0,lvl1,lvl2,reduction}) so CU packing
//    never stacks multiple heavy level-0 blocks on one CU.
//  * Contribution pass: compact selected (<=64) indices to LDS, then ONE
//    parallel pass (tid<64) -> single exposed memory round trip; atomicOr
//    decoupled from dependent loads.
//  * CAP 4096->1536 (LDS ~14 KB), float4 dense obj reduction.
// ---------------------------------------------------------------------------

#define K_SEL 64
#define CAP   1536
#define NBLK_TOT 1024       // 256 units x {lvl0, lvl1, lvl2, reduction}
#define NBLK_RED 256
#define TOTAL_PIX 688128.0f // 8*(65536+16384+4096)

typedef unsigned long long u64;

__device__ __forceinline__ float softplus_f(float x) {
    return fmaxf(x, 0.0f) + log1pf(expf(-fabsf(x)));
}

__device__ __forceinline__ float seg_dist(float px, float py,
                                          float x1, float y1, float x2, float y2) {
    float vx = x2 - x1, vy = y2 - y1;
    float wx = px - x1, wy = py - y1;
    float t = (wx * vx + wy * vy) / (vx * vx + vy * vy + 1e-9f);
    t = fminf(fmaxf(t, 0.0f), 1.0f);
    float dx = px - (x1 + t * vx), dy = py - (y1 + t * vy);
    return sqrtf(dx * dx + dy * dy + 1e-12f);
}

__device__ __forceinline__ bool tri_mask_dist(float px, float py,
    float Ax, float Ay, float Bx, float By, float Cx, float Cy, float* dout) {
    float d1 = (px - Bx) * (Ay - By) - (Ax - Bx) * (py - By);
    float d2 = (px - Cx) * (By - Cy) - (Bx - Cx) * (py - Cy);
    float d3 = (px - Ax) * (Cy - Ay) - (Cx - Ax) * (py - Ay);
    bool has_neg = (d1 < 0.f) || (d2 < 0.f) || (d3 < 0.f);
    bool has_pos = (d1 > 0.f) || (d2 > 0.f) || (d3 > 0.f);
    bool inside = !(has_neg && has_pos);
    float dist = fminf(seg_dist(px, py, Ax, Ay, Bx, By),
                 fminf(seg_dist(px, py, Bx, By, Cx, Cy),
                       seg_dist(px, py, Cx, Cy, Ax, Ay)));
    *dout = dist;
    return inside || (dist <= 3.0f);
}

// facc: [0]=reg_s [1]=cls_s [2]=obj_base [3]=obj_corr ; uacc: [0]=pos [1]=pos_now
__global__ __launch_bounds__(256)
void s25d_mega(const float* __restrict__ reg0, const float* __restrict__ obj0, const float* __restrict__ cls0,
               const float* __restrict__ reg1, const float* __restrict__ obj1, const float* __restrict__ cls1,
               const float* __restrict__ reg2, const float* __restrict__ obj2, const float* __restrict__ cls2,
               const float* __restrict__ gt,
               float* facc, unsigned* uacc, unsigned* done, unsigned* flags,
               float* out) {
    const int bid = blockIdx.x;
    const int tid = threadIdx.x;
    const int lane = tid & 63;
    const int wv = tid >> 6;
    const int type = bid & 3;     // 0,1,2 = selection levels; 3 = dense reduction
    const int unit = bid >> 2;    // 0..255

    __shared__ unsigned skey_hi[CAP];
    __shared__ unsigned skey_lo[CAP];
    __shared__ int scnt;
    __shared__ int hist[256];
    __shared__ int wtot[4];
    __shared__ int s_d, s_below, s_cnt;
    __shared__ int sel_hw[K_SEL];
    __shared__ int sel_n;
    __shared__ float red4[4];

    if (type < 3) {
        // -------------------- per-(level, b, g) selection block --------------------
        const int level = type;
        const int b = unit >> 5, g = unit & 31;

        const float* regp; const float* objp; const float* clsp;
        int Ws, log2Ws, flagBase; float stride;
        if (level == 0)      { regp = reg0; objp = obj0; clsp = cls0; Ws = 256; log2Ws = 8; stride =  8.f; flagBase = 0; }
        else if (level == 1) { regp = reg1; objp = obj1; clsp = cls1; Ws = 128; log2Ws = 7; stride = 16.f; flagBase = 16384; }
        else                 { regp = reg2; objp = obj2; clsp = cls2; Ws =  64; log2Ws = 6; stride = 32.f; flagBase = 20480; }
        const int HW = Ws * Ws;

        const float* tri = gt + (size_t)((b * 32 + g) * 3) * 2;
        const float Ax = tri[0], Ay = tri[1], Bx = tri[2], By = tri[3], Cx = tri[4], Cy = tri[5];

        if (tid == 0) { scnt = 0; sel_n = 0; }
        __syncthreads();

        // conservative bbox (+ETA, plus one-cell slack each side)
        float minx = fminf(Ax, fminf(Bx, Cx)) - 3.0f;
        float maxx = fmaxf(Ax, fmaxf(Bx, Cx)) + 3.0f;
        float miny = fminf(Ay, fminf(By, Cy)) - 3.0f;
        float maxy = fmaxf(Ay, fmaxf(By, Cy)) + 3.0f;
        int ix_lo = max(0,      (int)floorf(minx / stride - 0.5f));
        int ix_hi = min(Ws - 1, (int)ceilf (maxx / stride - 0.5f));
        int iy_lo = max(0,      (int)floorf(miny / stride - 0.5f));
        int iy_hi = min(Ws - 1, (int)ceilf (maxy / stride - 0.5f));
        int nx = ix_hi - ix_lo + 1, ny = iy_hi - iy_lo + 1;
        int ncells = (nx > 0 && ny > 0) ? nx * ny : 0;

        // ---- candidate collection (wave-aggregated LDS push) ----
        for (int base = 0; base < ncells; base += 256) {
            int c = base + tid;
            bool pred = false; unsigned dbits = 0; int idx = 0;
            if (c < ncells) {
                int ix = ix_lo + (c % nx);
                int iy = iy_lo + (c / nx);
                float px = (ix + 0.5f) * stride, py = (iy + 0.5f) * stride;
                float d;
                if (tri_mask_dist(px, py, Ax, Ay, Bx, By, Cx, Cy, &d)) {
                    pred = true;
                    dbits = __float_as_uint(d);      // d > 0 -> monotonic bits
                    idx = (iy << log2Ws) | ix;
                }
            }
            u64 m = __ballot(pred);
            if (m) {
                int rank = __popcll(m & ((1ull << lane) - 1));
                int total = __popcll(m);
                int fl = __ffsll((unsigned long long)m) - 1;
                int bs = 0;
                if (lane == fl) bs = atomicAdd(&scnt, total);
                bs = __shfl(bs, fl, 64);
                if (pred) {
                    int slot = bs + rank;
                    if (slot < CAP) { skey_hi[slot] = dbits; skey_lo[slot] = (unsigned)idx; }
                }
            }
        }
        __syncthreads();
        const int  cnt = scnt;
        const bool ovf = (cnt > CAP);
        const int  sel_cnt_exp = min(cnt, K_SEL);

        // ---- exact 64-bit radix select of the K-th smallest key ----
        u64 threshold = ~0ull;           // cnt<=K: everything selected
        if (cnt > K_SEL) {
            u64 prefix = 0;
            int need = K_SEL;
            const int lim = ovf ? ncells : cnt;
            for (int shift = 56; shift >= 0; shift -= 8) {
                hist[tid] = 0;
                __syncthreads();
                for (int base = 0; base < lim; base += 256) {
                    int c = base + tid;
                    if (c < lim) {
                        bool has = false; u64 key = 0;
                        if (!ovf) {
                            key = ((u64)skey_hi[c] << 32) | skey_lo[c];
                            has = true;
                        } else {
                            int ix = ix_lo + (c % nx);
                            int iy = iy_lo + (c / nx);
                            float px = (ix + 0.5f) * stride, py = (iy + 0.5f) * stride;
                            float d;
                            if (tri_mask_dist(px, py, Ax, Ay, Bx, By, Cx, Cy, &d)) {
                                key = ((u64)__float_as_uint(d) << 32) | (unsigned)((iy << log2Ws) | ix);
                                has = true;
                            }
                        }
                        if (has && (shift == 56 || (key >> (shift + 8)) == prefix))
                            atomicAdd(&hist[(int)((key >> shift) & 255)], 1);
                    }
                }
                __syncthreads();
                // 256-bin inclusive scan: shfl within wave, 4 wave totals via LDS
                int v = hist[tid];
                int x = v;
#pragma unroll
                for (int dlt = 1; dlt < 64; dlt <<= 1) {
                    int y = __shfl_up(x, dlt, 64);
                    if (lane >= dlt) x += y;
                }
                if (lane == 63) wtot[wv] = x;
                __syncthreads();
                int pre = 0;
                for (int i = 0; i < wv; ++i) pre += wtot[i];
                int cum = x + pre;
                int below = cum - v;
                if (cum >= need && below < need) { s_d = tid; s_below = below; s_cnt = v; }
                __syncthreads();
                int d = s_d, bl = s_below, bc = s_cnt;
                prefix = (prefix << 8) | (unsigned)d;
                if (bl + bc == need) {   // pivot bin count == remaining need -> exact
                    threshold = (prefix << shift) | (shift ? ((1ull << shift) - 1) : 0ull);
                    break;
                }
                need -= bl;
                // keys unique -> terminates by shift==0
            }
        }
        __syncthreads();

        // ---- compact selected (<= 64) indices into LDS ----
        {
            const int lim = ovf ? ncells : cnt;
            for (int base = 0; base < lim; base += 256) {
                int c = base + tid;
                bool take = false; int hw = 0;
                if (c < lim) {
                    if (!ovf) {
                        unsigned lo = skey_lo[c];
                        u64 key = ((u64)skey_hi[c] << 32) | lo;
                        take = (key <= threshold); hw = (int)lo;
                    } else {
                        int ix = ix_lo + (c % nx);
                        int iy = iy_lo + (c / nx);
                        float px = (ix + 0.5f) * stride, py = (iy + 0.5f) * stride;
                        float d;
                        if (tri_mask_dist(px, py, Ax, Ay, Bx, By, Cx, Cy, &d)) {
                            hw = (iy << log2Ws) | ix;
                            u64 key = ((u64)__float_as_uint(d) << 32) | (unsigned)hw;
                            take = (key <= threshold);
                        }
                    }
                }
                u64 m = __ballot(take);
                if (m) {
                    int rank = __popcll(m & ((1ull << lane) - 1));
                    int total = __popcll(m);
                    int fl = __ffsll((unsigned long long)m) - 1;
                    int bs = 0;
                    if (lane == fl) bs = atomicAdd(&sel_n, total);
                    bs = __shfl(bs, fl, 64);
                    if (take) {
                        int slot = bs + rank;
                        if (slot < K_SEL) sel_hw[slot] = hw;
                    }
                }
            }
        }
        __syncthreads();
        const int sn = min(sel_n, K_SEL);   // == sel_cnt_exp (exact threshold)
        (void)sel_cnt_exp;

        // ---- one-shot contribution: tid<sn, all memory ops parallel ----
        float my_reg = 0.f, my_cls = 0.f, my_corr = 0.f, my_first = 0.f;
        if (tid < sn) {
            int hw = sel_hw[tid];
            int ix = hw & (Ws - 1), iy = hw >> log2Ws;
            float ax = (ix + 0.5f) * stride, ay = (iy + 0.5f) * stride;
            int pix = b * HW + hw;

            int word = flagBase + (pix >> 5);
            unsigned bit = 1u << (pix & 31);
            unsigned old = atomicOr(&flags[word], bit);   // independent of loads below
            float xo = objp[pix];
            float xc = clsp[pix];
            float p[6];
#pragma unroll
            for (int ch = 0; ch < 6; ++ch) {
                float vv = regp[(size_t)(b * 6 + ch) * HW + hw];
                p[ch] = fminf(fmaxf(vv, -64.f), 64.f);
            }
            float first = (old & bit) ? 0.f : 1.f;
            my_first = first;
            my_corr = first * (1.2f * softplus_f(-xo) - softplus_f(xo));
            my_cls = softplus_f(-xc);

            float inv = 1.0f / stride;
            float g0x = (Ax - ax) * inv, g0y = (Ay - ay) * inv;
            float g1x = (Bx - ax) * inv, g1y = (By - ay) * inv;
            float g2x = (Cx - ax) * inv, g2y = (Cy - ay) * inv;
            float p0 = (p[0] - g0x) * (p[0] - g0x) + (p[1] - g0y) * (p[1] - g0y);
            float d00 = sqrtf((p[2] - g1x) * (p[2] - g1x) + (p[3] - g1y) * (p[3] - g1y));
            float d01 = sqrtf((p[2] - g2x) * (p[2] - g2x) + (p[3] - g2y) * (p[3] - g2y));
            float d10 = sqrtf((p[4] - g1x) * (p[4] - g1x) + (p[5] - g1y) * (p[5] - g1y));
            float d11 = sqrtf((p[4] - g2x) * (p[4] - g2x) + (p[5] - g2y) * (p[5] - g2y));
            float cd = fminf(d00, d01) + fminf(d10, d11) + fminf(d00, d10) + fminf(d01, d11);
            my_reg = p0 + cd;
        }

        // wave-0-only reduce (selected lanes are all in wave 0)
        if (wv == 0) {
#pragma unroll
            for (int dlt = 32; dlt > 0; dlt >>= 1) {
                my_reg   += __shfl_down(my_reg, dlt, 64);
                my_cls   += __shfl_down(my_cls, dlt, 64);
                my_corr  += __shfl_down(my_corr, dlt, 64);
                my_first += __shfl_down(my_first, dlt, 64);
            }
            if (lane == 0 && sn > 0) {
                atomicAdd(&facc[0], my_reg);
                atomicAdd(&facc[1], my_cls);
                atomicAdd(&facc[3], my_corr);
                atomicAdd(&uacc[0], (unsigned)sn);
                atomicAdd(&uacc[1], (unsigned)(my_first + 0.5f));
            }
        }
    } else {
        // -------------------- dense obj softplus base sum (float4) --------------------
        const int rb = unit;
        const float4* arrs[3] = { (const float4*)obj0, (const float4*)obj1, (const float4*)obj2 };
        const int    lens4[3] = { 131072, 32768, 8192 };
        float s = 0.f;
        for (int a = 0; a < 3; ++a) {
            const float4* p = arrs[a]; int n4 = lens4[a];
            for (int i = rb * 256 + tid; i < n4; i += NBLK_RED * 256) {
                float4 v = p[i];
                s += softplus_f(v.x) + softplus_f(v.y) + softplus_f(v.z) + softplus_f(v.w);
            }
        }
#pragma unroll
        for (int dlt = 32; dlt > 0; dlt >>= 1) s += __shfl_down(s, dlt, 64);
        if (lane == 0) red4[wv] = s;
        __syncthreads();
        if (tid == 0) atomicAdd(&facc[2], red4[0] + red4[1] + red4[2] + red4[3]);
    }

    // -------------------- fused finalize: last block computes total --------------------
    if (tid == 0) {
        __threadfence();
        unsigned prev = atomicAdd(done, 1u);
        if (prev == NBLK_TOT - 1) {
            float reg_s = atomicAdd(&facc[0], 0.0f);
            float cls_s = atomicAdd(&facc[1], 0.0f);
            float obj_s = atomicAdd(&facc[2], 0.0f) + atomicAdd(&facc[3], 0.0f);
            float pos = (float)atomicAdd(&uacc[0], 0u);
            float pos_now = (float)atomicAdd(&uacc[1], 0u);
            float neg = TOTAL_PIX - pos_now;
            float pos_eps = fmaxf(pos, 1.0f);
            float total = reg_s / pos_eps + obj_s / (pos_eps + fmaxf(neg, 1.0f)) + cls_s / pos_eps;
            out[0] = isfinite(total) ? total : 0.0f;
        }
    }
}

extern "C" void kernel_launch(void* const* d_in, const int* in_sizes, int n_in,
                              void* d_out, int out_size, void* d_ws, size_t ws_size,
                              hipStream_t stream) {
    const float* reg0 = (const float*)d_in[0];
    const float* obj0 = (const float*)d_in[1];
    const float* cls0 = (const float*)d_in[2];
    const float* reg1 = (const float*)d_in[3];
    const float* obj1 = (const float*)d_in[4];
    const float* cls1 = (const float*)d_in[5];
    const float* reg2 = (const float*)d_in[6];
    const float* obj2 = (const float*)d_in[7];
    const float* cls2 = (const float*)d_in[8];
    const float* gt   = (const float*)d_in[9];

    // ws layout: [0,16) float facc[4] | [16,24) uint uacc[2] | [24,28) uint done
    //            [64, 64+21504*4) flag bitmask (lvl0:16384w, lvl1:4096w, lvl2:1024w)
    float*    facc  = (float*)d_ws;
    unsigned* uacc  = (unsigned*)((char*)d_ws + 16);
    unsigned* done  = (unsigned*)((char*)d_ws + 24);
    unsigned* flags = (unsigned*)((char*)d_ws + 64);
    size_t clear_bytes = 64 + 21504 * 4;
    hipMemsetAsync(d_ws, 0, clear_bytes, stream);

    s25d_mega<<<dim3(NBLK_TOT), dim3(256), 0, stream>>>(
        reg0, obj0, cls0, reg1, obj1, cls1, reg2, obj2, cls2, gt,
        facc, uacc, done, flags, (float*)d_out);
}

// Round 4
// 130.924 us; speedup vs baseline: 1.1336x; 1.1336x over previous
//
#include <hip/hip_runtime.h>
#include <math.h>

// ---------------------------------------------------------------------------
// Strict2_5DLoss — 3-level triangle detection loss, forward only.
//
// R3 -> R4: removed per-block __threadfence() + done-counter finalize
// (device-scope fence on gfx950 = per-XCD L2 writeback+invalidate; 1024 of
// them serialized ≈ the whole 74 µs). Finalize is a separate 1-thread kernel
// again — kernel-boundary ordering gives the cross-XCD visibility once.
// Everything else identical to R3.
// ---------------------------------------------------------------------------

#define K_SEL 64
#define CAP   1536
#define NBLK_TOT 1024       // 256 units x {lvl0, lvl1, lvl2, reduction}
#define NBLK_RED 256
#define TOTAL_PIX 688128.0f // 8*(65536+16384+4096)

typedef unsigned long long u64;

__device__ __forceinline__ float softplus_f(float x) {
    return fmaxf(x, 0.0f) + log1pf(expf(-fabsf(x)));
}

__device__ __forceinline__ float seg_dist(float px, float py,
                                          float x1, float y1, float x2, float y2) {
    float vx = x2 - x1, vy = y2 - y1;
    float wx = px - x1, wy = py - y1;
    float t = (wx * vx + wy * vy) / (vx * vx + vy * vy + 1e-9f);
    t = fminf(fmaxf(t, 0.0f), 1.0f);
    float dx = px - (x1 + t * vx), dy = py - (y1 + t * vy);
    return sqrtf(dx * dx + dy * dy + 1e-12f);
}

__device__ __forceinline__ bool tri_mask_dist(float px, float py,
    float Ax, float Ay, float Bx, float By, float Cx, float Cy, float* dout) {
    float d1 = (px - Bx) * (Ay - By) - (Ax - Bx) * (py - By);
    float d2 = (px - Cx) * (By - Cy) - (Bx - Cx) * (py - Cy);
    float d3 = (px - Ax) * (Cy - Ay) - (Cx - Ax) * (py - Ay);
    bool has_neg = (d1 < 0.f) || (d2 < 0.f) || (d3 < 0.f);
    bool has_pos = (d1 > 0.f) || (d2 > 0.f) || (d3 > 0.f);
    bool inside = !(has_neg && has_pos);
    float dist = fminf(seg_dist(px, py, Ax, Ay, Bx, By),
                 fminf(seg_dist(px, py, Bx, By, Cx, Cy),
                       seg_dist(px, py, Cx, Cy, Ax, Ay)));
    *dout = dist;
    return inside || (dist <= 3.0f);
}

// facc: [0]=reg_s [1]=cls_s [2]=obj_base [3]=obj_corr ; uacc: [0]=pos [1]=pos_now
__global__ __launch_bounds__(256)
void s25d_mega(const float* __restrict__ reg0, const float* __restrict__ obj0, const float* __restrict__ cls0,
               const float* __restrict__ reg1, const float* __restrict__ obj1, const float* __restrict__ cls1,
               const float* __restrict__ reg2, const float* __restrict__ obj2, const float* __restrict__ cls2,
               const float* __restrict__ gt,
               float* facc, unsigned* uacc, unsigned* flags) {
    const int bid = blockIdx.x;
    const int tid = threadIdx.x;
    const int lane = tid & 63;
    const int wv = tid >> 6;
    const int type = bid & 3;     // 0,1,2 = selection levels; 3 = dense reduction
    const int unit = bid >> 2;    // 0..255

    __shared__ unsigned skey_hi[CAP];
    __shared__ unsigned skey_lo[CAP];
    __shared__ int scnt;
    __shared__ int hist[256];
    __shared__ int wtot[4];
    __shared__ int s_d, s_below, s_cnt;
    __shared__ int sel_hw[K_SEL];
    __shared__ int sel_n;
    __shared__ float red4[4];

    if (type < 3) {
        // -------------------- per-(level, b, g) selection block --------------------
        const int level = type;
        const int b = unit >> 5, g = unit & 31;

        const float* regp; const float* objp; const float* clsp;
        int Ws, log2Ws, flagBase; float stride;
        if (level == 0)      { regp = reg0; objp = obj0; clsp = cls0; Ws = 256; log2Ws = 8; stride =  8.f; flagBase = 0; }
        else if (level == 1) { regp = reg1; objp = obj1; clsp = cls1; Ws = 128; log2Ws = 7; stride = 16.f; flagBase = 16384; }
        else                 { regp = reg2; objp = obj2; clsp = cls2; Ws =  64; log2Ws = 6; stride = 32.f; flagBase = 20480; }
        const int HW = Ws * Ws;

        const float* tri = gt + (size_t)((b * 32 + g) * 3) * 2;
        const float Ax = tri[0], Ay = tri[1], Bx = tri[2], By = tri[3], Cx = tri[4], Cy = tri[5];

        if (tid == 0) { scnt = 0; sel_n = 0; }
        __syncthreads();

        // conservative bbox (+ETA, plus one-cell slack each side)
        float minx = fminf(Ax, fminf(Bx, Cx)) - 3.0f;
        float maxx = fmaxf(Ax, fmaxf(Bx, Cx)) + 3.0f;
        float miny = fminf(Ay, fminf(By, Cy)) - 3.0f;
        float maxy = fmaxf(Ay, fmaxf(By, Cy)) + 3.0f;
        int ix_lo = max(0,      (int)floorf(minx / stride - 0.5f));
        int ix_hi = min(Ws - 1, (int)ceilf (maxx / stride - 0.5f));
        int iy_lo = max(0,      (int)floorf(miny / stride - 0.5f));
        int iy_hi = min(Ws - 1, (int)ceilf (maxy / stride - 0.5f));
        int nx = ix_hi - ix_lo + 1, ny = iy_hi - iy_lo + 1;
        int ncells = (nx > 0 && ny > 0) ? nx * ny : 0;

        // ---- candidate collection (wave-aggregated LDS push) ----
        for (int base = 0; base < ncells; base += 256) {
            int c = base + tid;
            bool pred = false; unsigned dbits = 0; int idx = 0;
            if (c < ncells) {
                int ix = ix_lo + (c % nx);
                int iy = iy_lo + (c / nx);
                float px = (ix + 0.5f) * stride, py = (iy + 0.5f) * stride;
                float d;
                if (tri_mask_dist(px, py, Ax, Ay, Bx, By, Cx, Cy, &d)) {
                    pred = true;
                    dbits = __float_as_uint(d);      // d > 0 -> monotonic bits
                    idx = (iy << log2Ws) | ix;
                }
            }
            u64 m = __ballot(pred);
            if (m) {
                int rank = __popcll(m & ((1ull << lane) - 1));
                int total = __popcll(m);
                int fl = __ffsll((unsigned long long)m) - 1;
                int bs = 0;
                if (lane == fl) bs = atomicAdd(&scnt, total);
                bs = __shfl(bs, fl, 64);
                if (pred) {
                    int slot = bs + rank;
                    if (slot < CAP) { skey_hi[slot] = dbits; skey_lo[slot] = (unsigned)idx; }
                }
            }
        }
        __syncthreads();
        const int  cnt = scnt;
        const bool ovf = (cnt > CAP);

        // ---- exact 64-bit radix select of the K-th smallest key ----
        u64 threshold = ~0ull;           // cnt<=K: everything selected
        if (cnt > K_SEL) {
            u64 prefix = 0;
            int need = K_SEL;
            const int lim = ovf ? ncells : cnt;
            for (int shift = 56; shift >= 0; shift -= 8) {
                hist[tid] = 0;
                __syncthreads();
                for (int base = 0; base < lim; base += 256) {
                    int c = base + tid;
                    if (c < lim) {
                        bool has = false; u64 key = 0;
                        if (!ovf) {
                            key = ((u64)skey_hi[c] << 32) | skey_lo[c];
                            has = true;
                        } else {
                            int ix = ix_lo + (c % nx);
                            int iy = iy_lo + (c / nx);
                            float px = (ix + 0.5f) * stride, py = (iy + 0.5f) * stride;
                            float d;
                            if (tri_mask_dist(px, py, Ax, Ay, Bx, By, Cx, Cy, &d)) {
                                key = ((u64)__float_as_uint(d) << 32) | (unsigned)((iy << log2Ws) | ix);
                                has = true;
                            }
                        }
                        if (has && (shift == 56 || (key >> (shift + 8)) == prefix))
                            atomicAdd(&hist[(int)((key >> shift) & 255)], 1);
                    }
                }
                __syncthreads();
                // 256-bin inclusive scan: shfl within wave, 4 wave totals via LDS
                int v = hist[tid];
                int x = v;
#pragma unroll
                for (int dlt = 1; dlt < 64; dlt <<= 1) {
                    int y = __shfl_up(x, dlt, 64);
                    if (lane >= dlt) x += y;
                }
                if (lane == 63) wtot[wv] = x;
                __syncthreads();
                int pre = 0;
                for (int i = 0; i < wv; ++i) pre += wtot[i];
                int cum = x + pre;
                int below = cum - v;
                if (cum >= need && below < need) { s_d = tid; s_below = below; s_cnt = v; }
                __syncthreads();
                int d = s_d, bl = s_below, bc = s_cnt;
                prefix = (prefix << 8) | (unsigned)d;
                if (bl + bc == need) {   // pivot bin count == remaining need -> exact
                    threshold = (prefix << shift) | (shift ? ((1ull << shift) - 1) : 0ull);
                    break;
                }
                need -= bl;
                // keys unique -> terminates by shift==0
            }
        }
        __syncthreads();

        // ---- compact selected (<= 64) indices into LDS ----
        {
            const int lim = ovf ? ncells : cnt;
            for (int base = 0; base < lim; base += 256) {
                int c = base + tid;
                bool take = false; int hw = 0;
                if (c < lim) {
                    if (!ovf) {
                        unsigned lo = skey_lo[c];
                        u64 key = ((u64)skey_hi[c] << 32) | lo;
                        take = (key <= threshold); hw = (int)lo;
                    } else {
                        int ix = ix_lo + (c % nx);
                        int iy = iy_lo + (c / nx);
                        float px = (ix + 0.5f) * stride, py = (iy + 0.5f) * stride;
                        float d;
                        if (tri_mask_dist(px, py, Ax, Ay, Bx, By, Cx, Cy, &d)) {
                            hw = (iy << log2Ws) | ix;
                            u64 key = ((u64)__float_as_uint(d) << 32) | (unsigned)hw;
                            take = (key <= threshold);
                        }
                    }
                }
                u64 m = __ballot(take);
                if (m) {
                    int rank = __popcll(m & ((1ull << lane) - 1));
                    int total = __popcll(m);
                    int fl = __ffsll((unsigned long long)m) - 1;
                    int bs = 0;
                    if (lane == fl) bs = atomicAdd(&sel_n, total);
                    bs = __shfl(bs, fl, 64);
                    if (take) {
                        int slot = bs + rank;
                        if (slot < K_SEL) sel_hw[slot] = hw;
                    }
                }
            }
        }
        __syncthreads();
        const int sn = min(sel_n, K_SEL);

        // ---- one-shot contribution: tid<sn, all memory ops parallel ----
        float my_reg = 0.f, my_cls = 0.f, my_corr = 0.f, my_first = 0.f;
        if (tid < sn) {
            int hw = sel_hw[tid];
            int ix = hw & (Ws - 1), iy = hw >> log2Ws;
            float ax = (ix + 0.5f) * stride, ay = (iy + 0.5f) * stride;
            int pix = b * HW + hw;

            int word = flagBase + (pix >> 5);
            unsigned bit = 1u << (pix & 31);
            unsigned old = atomicOr(&flags[word], bit);   // independent of loads below
            float xo = objp[pix];
            float xc = clsp[pix];
            float p[6];
#pragma unroll
            for (int ch = 0; ch < 6; ++ch) {
                float vv = regp[(size_t)(b * 6 + ch) * HW + hw];
                p[ch] = fminf(fmaxf(vv, -64.f), 64.f);
            }
            float first = (old & bit) ? 0.f : 1.f;
            my_first = first;
            my_corr = first * (1.2f * softplus_f(-xo) - softplus_f(xo));
            my_cls = softplus_f(-xc);

            float inv = 1.0f / stride;
            float g0x = (Ax - ax) * inv, g0y = (Ay - ay) * inv;
            float g1x = (Bx - ax) * inv, g1y = (By - ay) * inv;
            float g2x = (Cx - ax) * inv, g2y = (Cy - ay) * inv;
            float p0 = (p[0] - g0x) * (p[0] - g0x) + (p[1] - g0y) * (p[1] - g0y);
            float d00 = sqrtf((p[2] - g1x) * (p[2] - g1x) + (p[3] - g1y) * (p[3] - g1y));
            float d01 = sqrtf((p[2] - g2x) * (p[2] - g2x) + (p[3] - g2y) * (p[3] - g2y));
            float d10 = sqrtf((p[4] - g1x) * (p[4] - g1x) + (p[5] - g1y) * (p[5] - g1y));
            float d11 = sqrtf((p[4] - g2x) * (p[4] - g2x) + (p[5] - g2y) * (p[5] - g2y));
            float cd = fminf(d00, d01) + fminf(d10, d11) + fminf(d00, d10) + fminf(d01, d11);
            my_reg = p0 + cd;
        }

        // wave-0-only reduce (selected lanes are all in wave 0)
        if (wv == 0) {
#pragma unroll
            for (int dlt = 32; dlt > 0; dlt >>= 1) {
                my_reg   += __shfl_down(my_reg, dlt, 64);
                my_cls   += __shfl_down(my_cls, dlt, 64);
                my_corr  += __shfl_down(my_corr, dlt, 64);
                my_first += __shfl_down(my_first, dlt, 64);
            }
            if (lane == 0 && sn > 0) {
                atomicAdd(&facc[0], my_reg);
                atomicAdd(&facc[1], my_cls);
                atomicAdd(&facc[3], my_corr);
                atomicAdd(&uacc[0], (unsigned)sn);
                atomicAdd(&uacc[1], (unsigned)(my_first + 0.5f));
            }
        }
    } else {
        // -------------------- dense obj softplus base sum (float4) --------------------
        const int rb = unit;
        const float4* arrs[3] = { (const float4*)obj0, (const float4*)obj1, (const float4*)obj2 };
        const int    lens4[3] = { 131072, 32768, 8192 };
        float s = 0.f;
        for (int a = 0; a < 3; ++a) {
            const float4* p = arrs[a]; int n4 = lens4[a];
            for (int i = rb * 256 + tid; i < n4; i += NBLK_RED * 256) {
                float4 v = p[i];
                s += softplus_f(v.x) + softplus_f(v.y) + softplus_f(v.z) + softplus_f(v.w);
            }
        }
#pragma unroll
        for (int dlt = 32; dlt > 0; dlt >>= 1) s += __shfl_down(s, dlt, 64);
        if (lane == 0) red4[wv] = s;
        __syncthreads();
        if (tid == 0) atomicAdd(&facc[2], red4[0] + red4[1] + red4[2] + red4[3]);
    }
}

__global__ void s25d_finalize(const float* facc, const unsigned* uacc, float* out) {
    float reg_s = facc[0];
    float cls_s = facc[1];
    float obj_s = facc[2] + facc[3];
    float pos = (float)uacc[0];
    float pos_now = (float)uacc[1];
    float neg = TOTAL_PIX - pos_now;
    float pos_eps = fmaxf(pos, 1.0f);
    float total = reg_s / pos_eps + obj_s / (pos_eps + fmaxf(neg, 1.0f)) + cls_s / pos_eps;
    out[0] = isfinite(total) ? total : 0.0f;
}

extern "C" void kernel_launch(void* const* d_in, const int* in_sizes, int n_in,
                              void* d_out, int out_size, void* d_ws, size_t ws_size,
                              hipStream_t stream) {
    const float* reg0 = (const float*)d_in[0];
    const float* obj0 = (const float*)d_in[1];
    const float* cls0 = (const float*)d_in[2];
    const float* reg1 = (const float*)d_in[3];
    const float* obj1 = (const float*)d_in[4];
    const float* cls1 = (const float*)d_in[5];
    const float* reg2 = (const float*)d_in[6];
    const float* obj2 = (const float*)d_in[7];
    const float* cls2 = (const float*)d_in[8];
    const float* gt   = (const float*)d_in[9];

    // ws layout: [0,16) float facc[4] | [16,24) uint uacc[2]
    //            [64, 64+21504*4) flag bitmask (lvl0:16384w, lvl1:4096w, lvl2:1024w)
    float*    facc  = (float*)d_ws;
    unsigned* uacc  = (unsigned*)((char*)d_ws + 16);
    unsigned* flags = (unsigned*)((char*)d_ws + 64);
    size_t clear_bytes = 64 + 21504 * 4;
    hipMemsetAsync(d_ws, 0, clear_bytes, stream);

    s25d_mega<<<dim3(NBLK_TOT), dim3(256), 0, stream>>>(
        reg0, obj0, cls0, reg1, obj1, cls1, reg2, obj2, cls2, gt,
        facc, uacc, flags);
    s25d_finalize<<<1, 1, 0, stream>>>(facc, uacc, (float*)d_out);
}

// Round 5
// 90.385 us; speedup vs baseline: 1.6421x; 1.4485x over previous
//
#include <hip/hip_runtime.h>
#include <math.h>

// ---------------------------------------------------------------------------
// Strict2_5DLoss — 3-level triangle detection loss, forward only.
//
// R4 -> R5: banked result accumulators. R4 had all six global counters in ONE
// 64 B line; 3840 device-scope atomics serialized on it (~15 ns each ≈ the
// whole 54 µs). Now 64 banks x 128 B (bank = bid & 63), six float counters
// per bank; finalize reduces the banks. Everything else identical to R4.
// ---------------------------------------------------------------------------

#define K_SEL 64
#define CAP   1536
#define NBLK_TOT 1024       // 256 units x {lvl0, lvl1, lvl2, reduction}
#define NBLK_RED 256
#define NBANK 64
#define BANK_STRIDE 32      // floats (128 B per bank)
// per-bank counter slots: 0=reg_s 1=cls_s 2=obj_corr 3=obj_base 4=pos 5=pos_now
#define TOTAL_PIX 688128.0f // 8*(65536+16384+4096)

typedef unsigned long long u64;

__device__ __forceinline__ float softplus_f(float x) {
    return fmaxf(x, 0.0f) + log1pf(expf(-fabsf(x)));
}

__device__ __forceinline__ float seg_dist(float px, float py,
                                          float x1, float y1, float x2, float y2) {
    float vx = x2 - x1, vy = y2 - y1;
    float wx = px - x1, wy = py - y1;
    float t = (wx * vx + wy * vy) / (vx * vx + vy * vy + 1e-9f);
    t = fminf(fmaxf(t, 0.0f), 1.0f);
    float dx = px - (x1 + t * vx), dy = py - (y1 + t * vy);
    return sqrtf(dx * dx + dy * dy + 1e-12f);
}

__device__ __forceinline__ bool tri_mask_dist(float px, float py,
    float Ax, float Ay, float Bx, float By, float Cx, float Cy, float* dout) {
    float d1 = (px - Bx) * (Ay - By) - (Ax - Bx) * (py - By);
    float d2 = (px - Cx) * (By - Cy) - (Bx - Cx) * (py - Cy);
    float d3 = (px - Ax) * (Cy - Ay) - (Cx - Ax) * (py - Ay);
    bool has_neg = (d1 < 0.f) || (d2 < 0.f) || (d3 < 0.f);
    bool has_pos = (d1 > 0.f) || (d2 > 0.f) || (d3 > 0.f);
    bool inside = !(has_neg && has_pos);
    float dist = fminf(seg_dist(px, py, Ax, Ay, Bx, By),
                 fminf(seg_dist(px, py, Bx, By, Cx, Cy),
                       seg_dist(px, py, Cx, Cy, Ax, Ay)));
    *dout = dist;
    return inside || (dist <= 3.0f);
}

__global__ __launch_bounds__(256)
void s25d_mega(const float* __restrict__ reg0, const float* __restrict__ obj0, const float* __restrict__ cls0,
               const float* __restrict__ reg1, const float* __restrict__ obj1, const float* __restrict__ cls1,
               const float* __restrict__ reg2, const float* __restrict__ obj2, const float* __restrict__ cls2,
               const float* __restrict__ gt,
               float* banks, unsigned* flags) {
    const int bid = blockIdx.x;
    const int tid = threadIdx.x;
    const int lane = tid & 63;
    const int wv = tid >> 6;
    const int type = bid & 3;     // 0,1,2 = selection levels; 3 = dense reduction
    const int unit = bid >> 2;    // 0..255
    float* bank = banks + (size_t)(bid & (NBANK - 1)) * BANK_STRIDE;

    __shared__ unsigned skey_hi[CAP];
    __shared__ unsigned skey_lo[CAP];
    __shared__ int scnt;
    __shared__ int hist[256];
    __shared__ int wtot[4];
    __shared__ int s_d, s_below, s_cnt;
    __shared__ int sel_hw[K_SEL];
    __shared__ int sel_n;
    __shared__ float red4[4];

    if (type < 3) {
        // -------------------- per-(level, b, g) selection block --------------------
        const int level = type;
        const int b = unit >> 5, g = unit & 31;

        const float* regp; const float* objp; const float* clsp;
        int Ws, log2Ws, flagBase; float stride;
        if (level == 0)      { regp = reg0; objp = obj0; clsp = cls0; Ws = 256; log2Ws = 8; stride =  8.f; flagBase = 0; }
        else if (level == 1) { regp = reg1; objp = obj1; clsp = cls1; Ws = 128; log2Ws = 7; stride = 16.f; flagBase = 16384; }
        else                 { regp = reg2; objp = obj2; clsp = cls2; Ws =  64; log2Ws = 6; stride = 32.f; flagBase = 20480; }
        const int HW = Ws * Ws;

        const float* tri = gt + (size_t)((b * 32 + g) * 3) * 2;
        const float Ax = tri[0], Ay = tri[1], Bx = tri[2], By = tri[3], Cx = tri[4], Cy = tri[5];

        if (tid == 0) { scnt = 0; sel_n = 0; }
        __syncthreads();

        // conservative bbox (+ETA, plus one-cell slack each side)
        float minx = fminf(Ax, fminf(Bx, Cx)) - 3.0f;
        float maxx = fmaxf(Ax, fmaxf(Bx, Cx)) + 3.0f;
        float miny = fminf(Ay, fminf(By, Cy)) - 3.0f;
        float maxy = fmaxf(Ay, fmaxf(By, Cy)) + 3.0f;
        int ix_lo = max(0,      (int)floorf(minx / stride - 0.5f));
        int ix_hi = min(Ws - 1, (int)ceilf (maxx / stride - 0.5f));
        int iy_lo = max(0,      (int)floorf(miny / stride - 0.5f));
        int iy_hi = min(Ws - 1, (int)ceilf (maxy / stride - 0.5f));
        int nx = ix_hi - ix_lo + 1, ny = iy_hi - iy_lo + 1;
        int ncells = (nx > 0 && ny > 0) ? nx * ny : 0;

        // ---- candidate collection (wave-aggregated LDS push) ----
        for (int base = 0; base < ncells; base += 256) {
            int c = base + tid;
            bool pred = false; unsigned dbits = 0; int idx = 0;
            if (c < ncells) {
                int ix = ix_lo + (c % nx);
                int iy = iy_lo + (c / nx);
                float px = (ix + 0.5f) * stride, py = (iy + 0.5f) * stride;
                float d;
                if (tri_mask_dist(px, py, Ax, Ay, Bx, By, Cx, Cy, &d)) {
                    pred = true;
                    dbits = __float_as_uint(d);      // d > 0 -> monotonic bits
                    idx = (iy << log2Ws) | ix;
                }
            }
            u64 m = __ballot(pred);
            if (m) {
                int rank = __popcll(m & ((1ull << lane) - 1));
                int total = __popcll(m);
                int fl = __ffsll((unsigned long long)m) - 1;
                int bs = 0;
                if (lane == fl) bs = atomicAdd(&scnt, total);
                bs = __shfl(bs, fl, 64);
                if (pred) {
                    int slot = bs + rank;
                    if (slot < CAP) { skey_hi[slot] = dbits; skey_lo[slot] = (unsigned)idx; }
                }
            }
        }
        __syncthreads();
        const int  cnt = scnt;
        const bool ovf = (cnt > CAP);

        // ---- exact 64-bit radix select of the K-th smallest key ----
        u64 threshold = ~0ull;           // cnt<=K: everything selected
        if (cnt > K_SEL) {
            u64 prefix = 0;
            int need = K_SEL;
            const int lim = ovf ? ncells : cnt;
            for (int shift = 56; shift >= 0; shift -= 8) {
                hist[tid] = 0;
                __syncthreads();
                for (int base = 0; base < lim; base += 256) {
                    int c = base + tid;
                    if (c < lim) {
                        bool has = false; u64 key = 0;
                        if (!ovf) {
                            key = ((u64)skey_hi[c] << 32) | skey_lo[c];
                            has = true;
                        } else {
                            int ix = ix_lo + (c % nx);
                            int iy = iy_lo + (c / nx);
                            float px = (ix + 0.5f) * stride, py = (iy + 0.5f) * stride;
                            float d;
                            if (tri_mask_dist(px, py, Ax, Ay, Bx, By, Cx, Cy, &d)) {
                                key = ((u64)__float_as_uint(d) << 32) | (unsigned)((iy << log2Ws) | ix);
                                has = true;
                            }
                        }
                        if (has && (shift == 56 || (key >> (shift + 8)) == prefix))
                            atomicAdd(&hist[(int)((key >> shift) & 255)], 1);
                    }
                }
                __syncthreads();
                // 256-bin inclusive scan: shfl within wave, 4 wave totals via LDS
                int v = hist[tid];
                int x = v;
#pragma unroll
                for (int dlt = 1; dlt < 64; dlt <<= 1) {
                    int y = __shfl_up(x, dlt, 64);
                    if (lane >= dlt) x += y;
                }
                if (lane == 63) wtot[wv] = x;
                __syncthreads();
                int pre = 0;
                for (int i = 0; i < wv; ++i) pre += wtot[i];
                int cum = x + pre;
                int below = cum - v;
                if (cum >= need && below < need) { s_d = tid; s_below = below; s_cnt = v; }
                __syncthreads();
                int d = s_d, bl = s_below, bc = s_cnt;
                prefix = (prefix << 8) | (unsigned)d;
                if (bl + bc == need) {   // pivot bin count == remaining need -> exact
                    threshold = (prefix << shift) | (shift ? ((1ull << shift) - 1) : 0ull);
                    break;
                }
                need -= bl;
                // keys unique -> terminates by shift==0
            }
        }
        __syncthreads();

        // ---- compact selected (<= 64) indices into LDS ----
        {
            const int lim = ovf ? ncells : cnt;
            for (int base = 0; base < lim; base += 256) {
                int c = base + tid;
                bool take = false; int hw = 0;
                if (c < lim) {
                    if (!ovf) {
                        unsigned lo = skey_lo[c];
                        u64 key = ((u64)skey_hi[c] << 32) | lo;
                        take = (key <= threshold); hw = (int)lo;
                    } else {
                        int ix = ix_lo + (c % nx);
                        int iy = iy_lo + (c / nx);
                        float px = (ix + 0.5f) * stride, py = (iy + 0.5f) * stride;
                        float d;
                        if (tri_mask_dist(px, py, Ax, Ay, Bx, By, Cx, Cy, &d)) {
                            hw = (iy << log2Ws) | ix;
                            u64 key = ((u64)__float_as_uint(d) << 32) | (unsigned)hw;
                            take = (key <= threshold);
                        }
                    }
                }
                u64 m = __ballot(take);
                if (m) {
                    int rank = __popcll(m & ((1ull << lane) - 1));
                    int total = __popcll(m);
                    int fl = __ffsll((unsigned long long)m) - 1;
                    int bs = 0;
                    if (lane == fl) bs = atomicAdd(&sel_n, total);
                    bs = __shfl(bs, fl, 64);
                    if (take) {
                        int slot = bs + rank;
                        if (slot < K_SEL) sel_hw[slot] = hw;
                    }
                }
            }
        }
        __syncthreads();
        const int sn = min(sel_n, K_SEL);

        // ---- one-shot contribution: tid<sn, all memory ops parallel ----
        float my_reg = 0.f, my_cls = 0.f, my_corr = 0.f, my_first = 0.f;
        if (tid < sn) {
            int hw = sel_hw[tid];
            int ix = hw & (Ws - 1), iy = hw >> log2Ws;
            float ax = (ix + 0.5f) * stride, ay = (iy + 0.5f) * stride;
            int pix = b * HW + hw;

            int word = flagBase + (pix >> 5);
            unsigned bit = 1u << (pix & 31);
            unsigned old = atomicOr(&flags[word], bit);   // independent of loads below
            float xo = objp[pix];
            float xc = clsp[pix];
            float p[6];
#pragma unroll
            for (int ch = 0; ch < 6; ++ch) {
                float vv = regp[(size_t)(b * 6 + ch) * HW + hw];
                p[ch] = fminf(fmaxf(vv, -64.f), 64.f);
            }
            float first = (old & bit) ? 0.f : 1.f;
            my_first = first;
            my_corr = first * (1.2f * softplus_f(-xo) - softplus_f(xo));
            my_cls = softplus_f(-xc);

            float inv = 1.0f / stride;
            float g0x = (Ax - ax) * inv, g0y = (Ay - ay) * inv;
            float g1x = (Bx - ax) * inv, g1y = (By - ay) * inv;
            float g2x = (Cx - ax) * inv, g2y = (Cy - ay) * inv;
            float p0 = (p[0] - g0x) * (p[0] - g0x) + (p[1] - g0y) * (p[1] - g0y);
            float d00 = sqrtf((p[2] - g1x) * (p[2] - g1x) + (p[3] - g1y) * (p[3] - g1y));
            float d01 = sqrtf((p[2] - g2x) * (p[2] - g2x) + (p[3] - g2y) * (p[3] - g2y));
            float d10 = sqrtf((p[4] - g1x) * (p[4] - g1x) + (p[5] - g1y) * (p[5] - g1y));
            float d11 = sqrtf((p[4] - g2x) * (p[4] - g2x) + (p[5] - g2y) * (p[5] - g2y));
            float cd = fminf(d00, d01) + fminf(d10, d11) + fminf(d00, d10) + fminf(d01, d11);
            my_reg = p0 + cd;
        }

        // wave-0-only reduce (selected lanes are all in wave 0)
        if (wv == 0) {
#pragma unroll
            for (int dlt = 32; dlt > 0; dlt >>= 1) {
                my_reg   += __shfl_down(my_reg, dlt, 64);
                my_cls   += __shfl_down(my_cls, dlt, 64);
                my_corr  += __shfl_down(my_corr, dlt, 64);
                my_first += __shfl_down(my_first, dlt, 64);
            }
            if (lane == 0 && sn > 0) {
                atomicAdd(&bank[0], my_reg);
                atomicAdd(&bank[1], my_cls);
                atomicAdd(&bank[2], my_corr);
                atomicAdd(&bank[4], (float)sn);
                atomicAdd(&bank[5], my_first);
            }
        }
    } else {
        // -------------------- dense obj softplus base sum (float4) --------------------
        const int rb = unit;
        const float4* arrs[3] = { (const float4*)obj0, (const float4*)obj1, (const float4*)obj2 };
        const int    lens4[3] = { 131072, 32768, 8192 };
        float s = 0.f;
        for (int a = 0; a < 3; ++a) {
            const float4* p = arrs[a]; int n4 = lens4[a];
            for (int i = rb * 256 + tid; i < n4; i += NBLK_RED * 256) {
                float4 v = p[i];
                s += softplus_f(v.x) + softplus_f(v.y) + softplus_f(v.z) + softplus_f(v.w);
            }
        }
#pragma unroll
        for (int dlt = 32; dlt > 0; dlt >>= 1) s += __shfl_down(s, dlt, 64);
        if (lane == 0) red4[wv] = s;
        __syncthreads();
        if (tid == 0) atomicAdd(&bank[3], red4[0] + red4[1] + red4[2] + red4[3]);
    }
}

__global__ void s25d_finalize(const float* banks, float* out) {
    // 64 threads: one bank each, then wave-reduce
    int t = threadIdx.x;
    const float* bk = banks + (size_t)t * BANK_STRIDE;
    float reg_s = bk[0], cls_s = bk[1], corr = bk[2], base = bk[3];
    float pos = bk[4], pos_now = bk[5];
#pragma unroll
    for (int dlt = 32; dlt > 0; dlt >>= 1) {
        reg_s   += __shfl_down(reg_s, dlt, 64);
        cls_s   += __shfl_down(cls_s, dlt, 64);
        corr    += __shfl_down(corr, dlt, 64);
        base    += __shfl_down(base, dlt, 64);
        pos     += __shfl_down(pos, dlt, 64);
        pos_now += __shfl_down(pos_now, dlt, 64);
    }
    if (t == 0) {
        float obj_s = base + corr;
        float neg = TOTAL_PIX - pos_now;
        float pos_eps = fmaxf(pos, 1.0f);
        float total = reg_s / pos_eps + obj_s / (pos_eps + fmaxf(neg, 1.0f)) + cls_s / pos_eps;
        out[0] = isfinite(total) ? total : 0.0f;
    }
}

extern "C" void kernel_launch(void* const* d_in, const int* in_sizes, int n_in,
                              void* d_out, int out_size, void* d_ws, size_t ws_size,
                              hipStream_t stream) {
    const float* reg0 = (const float*)d_in[0];
    const float* obj0 = (const float*)d_in[1];
    const float* cls0 = (const float*)d_in[2];
    const float* reg1 = (const float*)d_in[3];
    const float* obj1 = (const float*)d_in[4];
    const float* cls1 = (const float*)d_in[5];
    const float* reg2 = (const float*)d_in[6];
    const float* obj2 = (const float*)d_in[7];
    const float* cls2 = (const float*)d_in[8];
    const float* gt   = (const float*)d_in[9];

    // ws layout: [0, 8192) 64 accumulator banks x 128 B
    //            [8192, 8192+21504*4) flag bitmask (lvl0:16384w, lvl1:4096w, lvl2:1024w)
    float*    banks = (float*)d_ws;
    unsigned* flags = (unsigned*)((char*)d_ws + NBANK * BANK_STRIDE * sizeof(float));
    size_t clear_bytes = NBANK * BANK_STRIDE * sizeof(float) + 21504 * 4;
    hipMemsetAsync(d_ws, 0, clear_bytes, stream);

    s25d_mega<<<dim3(NBLK_TOT), dim3(256), 0, stream>>>(
        reg0, obj0, cls0, reg1, obj1, cls1, reg2, obj2, cls2, gt,
        banks, flags);
    s25d_finalize<<<1, 64, 0, stream>>>(banks, (float*)d_out);
}